// Round 5
// baseline (401.962 us; speedup 1.0000x reference)
//
#include <hip/hip_runtime.h>
#include <math.h>

#define B 32
#define LQ 512
#define LK 2048
#define D 768
#define D4 192   // D/4 float4s per row
#define NC 64    // k-chunks per batch (split-K for fused attention)
// rows per chunk = LK/NC = 32; rows per wave = 8 (4 waves/block)
#define SC 32    // sentence chunks per batch

// ---------------- K1a: partial[b,c,d] = sum over 16 q-rows ----------------
// grid (32, SC), block 192; coalesced writes, no atomics.
__global__ __launch_bounds__(192) void k_sum_part(const float4* __restrict__ sent,
                                                  float4* __restrict__ part4) {
    int b = blockIdx.x, qc = blockIdx.y;
    int d4 = threadIdx.x;  // 0..191
    const float4* p = sent + ((size_t)b * LQ + (size_t)qc * 16) * D4 + d4;
    float4 acc = make_float4(0.f, 0.f, 0.f, 0.f);
#pragma unroll
    for (int q = 0; q < 16; ++q) {
        float4 v = p[(size_t)q * D4];
        acc.x += v.x; acc.y += v.y; acc.z += v.z; acc.w += v.w;
    }
    part4[((size_t)b * SC + qc) * D4 + d4] = acc;
}

// ---------------- K1b: s_sum[b,d] = sum_c partial[b,c,d] ----------------
// grid (32,3), block 256.
__global__ __launch_bounds__(256) void k_sum_reduce(const float* __restrict__ part,
                                                    float* __restrict__ s_sum) {
    int b = blockIdx.x;
    int d = blockIdx.y * 256 + threadIdx.x;
    float acc = 0.f;
#pragma unroll 8
    for (int c = 0; c < SC; ++c)
        acc += part[((size_t)b * SC + c) * D + d];
    s_sum[b * D + d] = acc;
}

// ---------------- K2a / K6: y[b,e] = dot(x[b,:], W[e,:]) + bias_scale*bias[e]
__global__ __launch_bounds__(256) void k_rowdot(const float4* __restrict__ x4,
                                                const float4* __restrict__ W4,
                                                const float* __restrict__ bias,
                                                float bias_scale,
                                                float* __restrict__ y) {
    int w = blockIdx.x * 4 + (threadIdx.x >> 6);   // 0..24575
    int lane = threadIdx.x & 63;
    int b = w / D, e = w % D;
    const float4* xr = x4 + (size_t)b * D4;
    const float4* wr = W4 + (size_t)e * D4;
    float acc = 0.f;
#pragma unroll
    for (int i = 0; i < 3; ++i) {
        int idx = lane + i * 64;
        float4 a = xr[idx], q = wr[idx];
        acc += a.x * q.x + a.y * q.y + a.z * q.z + a.w * q.w;
    }
#pragma unroll
    for (int off = 32; off; off >>= 1) acc += __shfl_down(acc, off, 64);
    if (lane == 0) y[w] = acc + bias_scale * bias[e];
}

// ---------------- K2b: wk[b,d] = sum_e q_sum[b,e] * Wk[e,d] ----------------
__global__ __launch_bounds__(256) void k_qsum_Wk(const float* __restrict__ q_sum,
                                                 const float* __restrict__ Wk,
                                                 float* __restrict__ wk) {
    int b = blockIdx.x;
    int d = blockIdx.y * 256 + threadIdx.x;
    const float* qs = q_sum + b * D;
    float acc = 0.f;
#pragma unroll 8
    for (int e = 0; e < D; ++e)
        acc += qs[e] * Wk[(size_t)e * D + d];
    wk[b * D + d] = acc;
}

// ---------------- K3: fused scores + online softmax + weighted sum --------
// grid (32, NC), block 256 (4 waves x 8 rows). Row kept in registers;
// online-softmax state (m, l, 768-wide acc = 3 float4/lane). Software
// prefetch of next row. Block-combines 4 waves in LDS; one partial/chunk.
__global__ __launch_bounds__(256) void k_attn(const float4* __restrict__ com4,
                                              const float* __restrict__ wk,
                                              float* __restrict__ pv,
                                              float* __restrict__ pm,
                                              float* __restrict__ pl) {
    __shared__ float sm[4], sl[4];
    __shared__ float sacc[4][D];
    int b = blockIdx.x, chunk = blockIdx.y;
    int tid = threadIdx.x, lane = tid & 63, w = tid >> 6;

    const float4* q4 = (const float4*)(wk + (size_t)b * D);
    float4 q0 = q4[lane], q1 = q4[lane + 64], q2 = q4[lane + 128];

    int row0 = chunk * 32 + w * 8;
    const float4* base = com4 + ((size_t)b * LK + row0) * D4;

    float m = -INFINITY, l = 0.f;
    float4 A0 = make_float4(0.f, 0.f, 0.f, 0.f);
    float4 A1 = make_float4(0.f, 0.f, 0.f, 0.f);
    float4 A2 = make_float4(0.f, 0.f, 0.f, 0.f);

    float4 c0 = base[lane], c1 = base[lane + 64], c2 = base[lane + 128];
#pragma unroll
    for (int r = 0; r < 8; ++r) {
        float4 n0, n1, n2;
        if (r < 7) {
            const float4* nb = base + (size_t)(r + 1) * D4;
            n0 = nb[lane]; n1 = nb[lane + 64]; n2 = nb[lane + 128];
        }
        float s = c0.x * q0.x + c0.y * q0.y + c0.z * q0.z + c0.w * q0.w
                + c1.x * q1.x + c1.y * q1.y + c1.z * q1.z + c1.w * q1.w
                + c2.x * q2.x + c2.y * q2.y + c2.z * q2.z + c2.w * q2.w;
#pragma unroll
        for (int off = 32; off; off >>= 1) s += __shfl_xor(s, off, 64);
        if (s <= m) {                       // wave-uniform branch
            float p = __expf(s - m);
            l += p;
            A0.x += p * c0.x; A0.y += p * c0.y; A0.z += p * c0.z; A0.w += p * c0.w;
            A1.x += p * c1.x; A1.y += p * c1.y; A1.z += p * c1.z; A1.w += p * c1.w;
            A2.x += p * c2.x; A2.y += p * c2.y; A2.z += p * c2.z; A2.w += p * c2.w;
        } else {                            // new max: rescale (exp(-inf)=0 on iter 0)
            float f = __expf(m - s);
            l = l * f + 1.f;
            A0.x = A0.x * f + c0.x; A0.y = A0.y * f + c0.y; A0.z = A0.z * f + c0.z; A0.w = A0.w * f + c0.w;
            A1.x = A1.x * f + c1.x; A1.y = A1.y * f + c1.y; A1.z = A1.z * f + c1.z; A1.w = A1.w * f + c1.w;
            A2.x = A2.x * f + c2.x; A2.y = A2.y * f + c2.y; A2.z = A2.z * f + c2.z; A2.w = A2.w * f + c2.w;
            m = s;
        }
        c0 = n0; c1 = n1; c2 = n2;
    }

    if (lane == 0) { sm[w] = m; sl[w] = l; }
    float4* sa = (float4*)sacc[w];
    sa[lane] = A0; sa[lane + 64] = A1; sa[lane + 128] = A2;
    __syncthreads();

    float M = fmaxf(fmaxf(sm[0], sm[1]), fmaxf(sm[2], sm[3]));
    float e0 = __expf(sm[0] - M), e1 = __expf(sm[1] - M);
    float e2 = __expf(sm[2] - M), e3 = __expf(sm[3] - M);
    float L = sl[0] * e0 + sl[1] * e1 + sl[2] * e2 + sl[3] * e3;

    int col = tid * 3;  // 256 threads x 3 cols = 768
    float* dst = pv + ((size_t)b * NC + chunk) * D;
#pragma unroll
    for (int j = 0; j < 3; ++j) {
        int c = col + j;
        dst[c] = sacc[0][c] * e0 + sacc[1][c] * e1 + sacc[2][c] * e2 + sacc[3][c] * e3;
    }
    if (tid == 0) { pm[b * NC + chunk] = M; pl[b * NC + chunk] = L; }
}

// ---------------- K4: merge split-K partials -> ctx[b,e] ----------------
__global__ __launch_bounds__(256) void k_merge(const float* __restrict__ pv,
                                               const float* __restrict__ pm,
                                               const float* __restrict__ pl,
                                               float* __restrict__ ctx) {
    __shared__ float spm[NC], spl[NC];
    int b = blockIdx.x, tid = threadIdx.x;
    if (tid < NC) { spm[tid] = pm[b * NC + tid]; spl[tid] = pl[b * NC + tid]; }
    __syncthreads();
    float M = -INFINITY;
#pragma unroll
    for (int c = 0; c < NC; ++c) M = fmaxf(M, spm[c]);
    float L = 0.f;
#pragma unroll
    for (int c = 0; c < NC; ++c) L += spl[c] * __expf(spm[c] - M);
    float inv = 1.f / L;
    int col = tid * 3;
    float o0 = 0.f, o1 = 0.f, o2 = 0.f;
    for (int c = 0; c < NC; ++c) {
        float e = __expf(spm[c] - M);
        const float* p = pv + ((size_t)b * NC + c) * D + col;
        o0 += e * p[0]; o1 += e * p[1]; o2 += e * p[2];
    }
    ctx[b * D + col] = o0 * inv;
    ctx[b * D + col + 1] = o1 * inv;
    ctx[b * D + col + 2] = o2 * inv;
}

extern "C" void kernel_launch(void* const* d_in, const int* in_sizes, int n_in,
                              void* d_out, int out_size, void* d_ws, size_t ws_size,
                              hipStream_t stream) {
    const float* sent = (const float*)d_in[0];   // [32,512,768]
    const float* com  = (const float*)d_in[1];   // [32,2048,768]
    const float* Wq   = (const float*)d_in[2];   // [768,768]
    const float* bq   = (const float*)d_in[3];   // [768]
    const float* Wk   = (const float*)d_in[4];
    // d_in[5] = bk: dropped (softmax-invariant constant per b)
    const float* Wv   = (const float*)d_in[6];
    const float* bv   = (const float*)d_in[7];
    float* out = (float*)d_out;

    // workspace layout (floats) — no zero-init needed anywhere
    float* ws = (float*)d_ws;
    float* part  = ws;                   // 32*SC*768 = 786432
    float* s_sum = ws + 786432;          // 24576
    float* q_sum = ws + 811008;          // 24576
    float* wk    = ws + 835584;          // 24576
    float* ctx   = ws + 860160;          // 24576
    float* pm    = ws + 884736;          // 2048
    float* pl    = ws + 886784;          // 2048
    float* pv    = ws + 888832;          // 32*NC*768 = 1572864

    // K1: sentence sum (partials -> reduce), no atomics
    k_sum_part<<<dim3(B, SC), 192, 0, stream>>>((const float4*)sent, (float4*)part);
    k_sum_reduce<<<dim3(B, 3), 256, 0, stream>>>(part, s_sum);

    // K2a: q_sum = s_sum @ Wq^T + 512*bq
    k_rowdot<<<6144, 256, 0, stream>>>((const float4*)s_sum, (const float4*)Wq,
                                       bq, (float)LQ, q_sum);

    // K2b: wk = q_sum @ Wk
    k_qsum_Wk<<<dim3(B, 3), 256, 0, stream>>>(q_sum, Wk, wk);

    // K3: fused scores + online softmax + weighted sum (comment read ONCE)
    k_attn<<<dim3(B, NC), 256, 0, stream>>>((const float4*)com, wk, pv, pm, pl);

    // K4: merge partials -> ctx
    k_merge<<<B, 256, 0, stream>>>(pv, pm, pl, ctx);

    // K6: out = ctx @ Wv^T + bv
    k_rowdot<<<6144, 256, 0, stream>>>((const float4*)ctx, (const float4*)Wv,
                                       bv, 1.0f, out);
}